// Round 22
// baseline (359.963 us; speedup 1.0000x reference)
//
#include <hip/hip_runtime.h>
#include <hip/hip_bf16.h>
#include <cstdint>

#define P_ 88   // pitches (sequence length of the scan)
#define B_ 16   // batch
#define T_ 256  // timesteps (folded into batch N)
#define H_ 188  // per-pitch features
#define G_ 192  // 4*48 gates; also LSTM1 input size (188 feat + 4 ctx)
#define U_ 48   // LSTM units
#define N_ 4096 // B_*T_

#define L2E 1.44269504f   // log2(e)
#define L2E2 2.88539008f  // 2*log2(e)

typedef __attribute__((ext_vector_type(8))) _Float16 f16x8;
typedef __attribute__((ext_vector_type(4))) float f32x4;

extern "C" __device__ float __ocml_native_exp2_f32(float);  // pure v_exp_f32

// prescaled-argument activations: y carries the log2e (or 2*log2e) factor
__device__ __forceinline__ float sig2(float y) {   // sigmoid, y = log2e*x
  return __builtin_amdgcn_rcpf(1.0f + __ocml_native_exp2_f32(-y));
}
__device__ __forceinline__ float tanh2g(float y) { // tanh, y = 2*log2e*x
  return 1.0f - 2.0f * __builtin_amdgcn_rcpf(1.0f + __ocml_native_exp2_f32(y));
}
__device__ __forceinline__ float tanh_c(float x) { // tanh, x linear (c-state)
  return 1.0f - 2.0f * __builtin_amdgcn_rcpf(1.0f + __ocml_native_exp2_f32(x * L2E2));
}

// Relaxed workgroup barrier: waits only on LDS ops (lgkmcnt), NOT vmcnt —
// global loads issued before it stay in flight across it.
__device__ __forceinline__ void lds_barrier() {
  asm volatile("s_waitcnt lgkmcnt(0)\n\ts_barrier" ::: "memory");
}

// ---------------------------------------------------------------------------
// Kernel 1: context MLP -> per-(b,p) gate bias vector (incl. bih1+bhh1),
// PRESCALED by log2e (2*log2e for the g-gate rows 96-143) for exp2 acts.
// ---------------------------------------------------------------------------
__global__ void ctx_kernel(const float* __restrict__ pc,
                           const float* __restrict__ fc1w, const float* __restrict__ fc1b,
                           const float* __restrict__ fc2w, const float* __restrict__ fc2b,
                           const float* __restrict__ fc3w, const float* __restrict__ fc3b,
                           const float* __restrict__ wih1,
                           const float* __restrict__ bih1, const float* __restrict__ bhh1,
                           float* __restrict__ ctxg) {
  int bp = blockIdx.x * 64 + threadIdx.x;
  if (bp >= B_ * P_) return;
  float p0 = pc[bp * 3 + 0], p1 = pc[bp * 3 + 1], p2 = pc[bp * 3 + 2];
  float x1[16], x2[16];
#pragma unroll
  for (int jj = 0; jj < 16; ++jj)
    x1[jj] = fmaxf(0.f, fc1w[jj * 3 + 0] * p0 + fc1w[jj * 3 + 1] * p1 + fc1w[jj * 3 + 2] * p2 + fc1b[jj]);
#pragma unroll
  for (int jj = 0; jj < 16; ++jj) {
    float s = fc2b[jj];
#pragma unroll
    for (int i = 0; i < 16; ++i) s += fc2w[jj * 16 + i] * x1[i];
    x2[jj] = fmaxf(0.f, s);
  }
  float ce[4];
#pragma unroll
  for (int jj = 0; jj < 4; ++jj) {
    float s = fc3b[jj];
#pragma unroll
    for (int i = 0; i < 16; ++i) s += fc3w[jj * 16 + i] * x2[i];
    ce[jj] = s;
  }
  float* op = ctxg + (size_t)bp * G_;
  for (int g = 0; g < G_; ++g) {
    const float* wr = wih1 + (size_t)g * G_ + H_;
    const float ws = ((g / 48) == 2) ? L2E2 : L2E;
    op[g] = ws * (bih1[g] + bhh1[g] + ce[0] * wr[0] + ce[1] * wr[1] + ce[2] * wr[2] + ce[3] * wr[3]);
  }
}

// ---------------------------------------------------------------------------
// Kernel 2: FUSED scan + PAIRED input GEMM + XCD swizzle (round 21)
// + round 22: (a) exp2 weight prescaling — all gate weights/biases carry
// log2e (g-gate: 2*log2e), activations use raw v_exp_f32 (saves 4 muls of
// 5 transcendentals per task); (b) s_setprio removed (2-block priority
// inversion hypothesis).
// ---------------------------------------------------------------------------
__global__ __launch_bounds__(256, 2) void scan_fused(
    const float* __restrict__ pf, const float* __restrict__ ctxg,
    const float* __restrict__ wih1, const float* __restrict__ whh1,
    const float* __restrict__ wih2, const float* __restrict__ whh2,
    const float* __restrict__ bih2, const float* __restrict__ bhh2,
    const float* __restrict__ fcw, const float* __restrict__ fcb,
    float* __restrict__ out) {
  __shared__ __align__(16) _Float16 h12[16][104];  // cols 0-47 h1, 48-95 h2
  __shared__ __align__(16) float gs1[8][196];      // L1 gate staging
  __shared__ __align__(16) float gs2[8][196];      // L2 gate staging
  __shared__ __align__(16) float h2f[8][52];       // h2 fp32 for fc_states
  __shared__ __align__(16) float fcws[5 * 48];
  __shared__ float logit_s[5][8];
  __shared__ float prob_s[5][8];
  // pf pair buffers: rows 0-7 = even slice, rows 8-15 = odd slice of pair m;
  // buffer index = m & 1.
  __shared__ __align__(16) _Float16 pfhi[2][16][200];
  __shared__ __align__(16) _Float16 pflo[2][16][200];

  const int tid = threadIdx.x;
  const int w = tid >> 6, l = tid & 63;
  const int lj = l & 15, lq = l >> 4;
  // XCD-aware bijective swizzle (512 blocks, chunk 64): XCD x owns batches
  // 2x, 2x+1 -> same-b scattered pf reads dedupe in that XCD's L2.
  const int g512 = (blockIdx.x & 7) * 64 + (blockIdx.x >> 3);
  const int n0 = g512 * 8;
  const int b = n0 >> 8, t0 = n0 & 255;

  // ---- persistent weight B-fragments (f16), PRESCALED for exp2 acts.
  // Gate type of column j = w*48+i*16+lj is t = w (wave-uniform!).
  const float wsc = (w == 2) ? L2E2 : L2E;
  f16x8 b1[3][2];    // whh1 cols, K=48 pad 64
  f16x8 b2f[3][3];   // [wih2; whh2] cols, K=96
  f16x8 wf[3][6];    // wih1 feature cols, K=188 pad 192
  float bias2r[3];
#pragma unroll
  for (int i = 0; i < 3; ++i) {
    const int j = w * 48 + i * 16 + lj;
    bias2r[i] = (bih2[j] + bhh2[j]) * wsc;
#pragma unroll
    for (int kc = 0; kc < 2; ++kc)
#pragma unroll
      for (int e = 0; e < 8; ++e) {
        const int u = kc * 32 + lq * 8 + e;
        b1[i][kc][e] = (u < U_) ? (_Float16)(whh1[j * U_ + u] * wsc) : (_Float16)0.f;
      }
#pragma unroll
    for (int kc = 0; kc < 3; ++kc)
#pragma unroll
      for (int e = 0; e < 8; ++e) {
        const int k = kc * 32 + lq * 8 + e;
        b2f[i][kc][e] = (k < U_) ? (_Float16)(wih2[j * U_ + k] * wsc)
                                 : (_Float16)(whh2[j * U_ + (k - U_)] * wsc);
      }
#pragma unroll
    for (int kc = 0; kc < 6; ++kc)
#pragma unroll
      for (int e = 0; e < 8; ++e) {
        const int k = kc * 32 + lq * 8 + e;
        wf[i][kc][e] = (k < H_) ? (_Float16)(wih1[(size_t)j * G_ + k] * wsc) : (_Float16)0.f;
      }
  }

  // ---- zero LDS state, load fc weights ----
  for (int e = tid; e < 16 * 104 / 2; e += 256) ((unsigned*)h12)[e] = 0u;
  for (int e = tid; e < 3200; e += 256) {  // 2*16*200 halves = 3200 uints each
    ((unsigned*)pfhi)[e] = 0u;
    ((unsigned*)pflo)[e] = 0u;
  }
  for (int e = tid; e < 5 * U_; e += 256) fcws[e] = fcw[e];
  lds_barrier();  // zeros complete before staging writes

  // ---- BALANCED activation tasks: flat f = tid, tid+256, tid+512 over
  // 768 = [0,384) L2 + [384,768) L1. Slot types are wave-uniform.
  const int s0n = tid / U_, s0u = tid % U_;                 // L2
  const bool s1L2 = (tid < 128);
  const int s1f = s1L2 ? (tid + 256) : (tid - 128);
  const int s1n = s1f / U_, s1u = s1f % U_;                 // L2 or L1
  const int s2n = (tid + 128) / U_, s2u = (tid + 128) % U_; // L1
  float cS0 = 0.f, cS1 = 0.f, cS2 = 0.f;  // c-state per slot

  // aux roles: fc lanes 40-49 of EVERY wave; store tid 96-135; softmax 192-199.
  const bool fcth = (l >= 40 && l < 50);
  const int fi = w * 10 + (l - 40);
  const int fk = (fi >> 3) < 5 ? (fi >> 3) : 0, fn = fi & 7;
  const float fcbr = fcth ? fcb[fk] : 0.f;
  const bool stth = tid >= 96 && tid < 136;
  const int sk = (tid - 96) >> 3, sn = (tid - 96) & 7;
  const bool smth = tid >= 192 && tid < 200;
  const int smn = tid - 192;

  // ---- pf staging coords: thread covers (h = tid/8 + 32*it, t = t0 + tid%8) ----
  const int sh = tid >> 3, stl = tid & 7;
  const float* pfb = pf + (size_t)b * P_ * H_ * T_ + (size_t)sh * T_ + t0 + stl;

  // prologue: stage slices 0,1 -> buf0 rows {0-7},{8-15}; slices 2,3 -> buf1
#pragma unroll
  for (int s = 0; s < 4; ++s) {
    const int bufi = (s >> 1) & 1, row = (s & 1) * 8 + stl;
    const float* sp = pfb + (size_t)s * H_ * T_;
#pragma unroll
    for (int it = 0; it < 6; ++it) {
      const int h = sh + it * 32;
      if (h < H_) {
        const float v = sp[(size_t)it * 32 * T_];
        const _Float16 hi = (_Float16)v;
        pfhi[bufi][row][h] = hi;
        pflo[bufi][row][h] = (_Float16)(v - (float)hi);
      }
    }
  }
  lds_barrier();

  // ctx-bias pointer (gate column w*48+i*16+lj)
  const float* cgbase = ctxg + (size_t)b * P_ * G_ + w * 48 + lj;

// INGEMM over pair buffer RB: C init = per-lane-half biases (CE/CO arrays)
#define INGEMM(ACC, RB, CE, CO)                                                \
  {                                                                            \
    _Pragma("unroll") for (int i = 0; i < 3; ++i) {                            \
      const float bsel = (l < 32) ? (CE)[i] : (CO)[i];                         \
      ACC[i][0] = bsel; ACC[i][1] = bsel; ACC[i][2] = bsel; ACC[i][3] = bsel;  \
    }                                                                          \
    _Pragma("unroll") for (int c = 0; c < 6; ++c) {                            \
      const f16x8 ah = *(const f16x8*)&pfhi[RB][lj][c * 32 + lq * 8];          \
      const f16x8 al = *(const f16x8*)&pflo[RB][lj][c * 32 + lq * 8];          \
      ACC[0] = __builtin_amdgcn_mfma_f32_16x16x32_f16(ah, wf[0][c], ACC[0], 0, 0, 0); \
      ACC[1] = __builtin_amdgcn_mfma_f32_16x16x32_f16(ah, wf[1][c], ACC[1], 0, 0, 0); \
      ACC[2] = __builtin_amdgcn_mfma_f32_16x16x32_f16(ah, wf[2][c], ACC[2], 0, 0, 0); \
      ACC[0] = __builtin_amdgcn_mfma_f32_16x16x32_f16(al, wf[0][c], ACC[0], 0, 0, 0); \
      ACC[1] = __builtin_amdgcn_mfma_f32_16x16x32_f16(al, wf[1][c], ACC[1], 0, 0, 0); \
      ACC[2] = __builtin_amdgcn_mfma_f32_16x16x32_f16(al, wf[2][c], ACC[2], 0, 0, 0); \
    }                                                                          \
  }

  // prologue production: pair 0 -> xgA = xg(0) (lanes l<32), xgB = xg(1)
  f32x4 xgA[3], xgB[3];
  {
    float cgE[3], cgO[3];
#pragma unroll
    for (int i = 0; i < 3; ++i) { cgE[i] = cgbase[i * 16]; cgO[i] = cgbase[G_ + i * 16]; }
    f32x4 xgP[3];
    INGEMM(xgP, 0, cgE, cgO);
#pragma unroll
    for (int i = 0; i < 3; ++i) {
      xgA[i] = xgP[i];
#pragma unroll
      for (int r = 0; r < 4; ++r) xgB[i][r] = __shfl_xor((float)xgP[i][r], 32);
    }
  }
  lds_barrier();  // buf0 reads complete before iter-0 staging rewrites it

  // cg for pair 1 (slices 2,3), preloaded; cgp points at pair 2 onward
  float cgCE[3], cgCO[3];
#pragma unroll
  for (int i = 0; i < 3; ++i) {
    cgCE[i] = cgbase[2 * G_ + i * 16];
    cgCO[i] = cgbase[3 * G_ + i * 16];
  }
  const float* cgp = cgbase + 4 * G_;

  // pf value carry registers: pvC = slice p+4 (written this iter),
  // pvN = slice p+5 (issued this iter, written next iter).
  float pvC[6], pvN[6];
#pragma unroll
  for (int it = 0; it < 6; ++it) { pvC[it] = 0.f; pvN[it] = 0.f; }
  const float* pfstage = pfb + (size_t)4 * H_ * T_;   // slice 4 onward

  for (int p = -1; p < P_; ++p) {
    const bool doL2 = (p >= 0), doL1 = (p < P_ - 1);
    const bool doProd = ((p & 1) == 0) && (p <= 84);   // pair (p+2, p+3)
    const bool doWrite = (p >= 0 && p <= 83);          // LDS-write slice p+4
    const bool doIssue = (p <= 82);                    // issue loads slice p+5
    const int prodRB = ((p + 2) >> 1) & 1;
    const int stgRB = ((p + 4) >> 1) & 1, stgRow = ((p + 4) & 1) * 8 + stl;

    // ---- write pvC (slice p+4, loaded LAST iter -> latency already hidden) ----
    if (doWrite) {
#pragma unroll
      for (int it = 0; it < 6; ++it) {
        const int h = sh + it * 32;
        if (h < H_) {
          const _Float16 hi = (_Float16)pvC[it];
          pfhi[stgRB][stgRow][h] = hi;
          pflo[stgRB][stgRow][h] = (_Float16)(pvC[it] - (float)hi);
        }
      }
    }
    // ---- issue slice p+5 loads; consumed next iteration (cross-barrier) ----
    if (doIssue) {
#pragma unroll
      for (int it = 0; it < 6; ++it)
        pvN[it] = (sh + it * 32 < H_) ? pfstage[(size_t)it * 32 * T_] : 0.f;
      pfstage += (size_t)H_ * T_;
    }

    // ================= M: MFMA phase =================
    const _Float16* hr = &h12[lj][0];
    const f16x8 f0 = *(const f16x8*)(hr + lq * 8);        // h1 k0-31
    const f16x8 f1 = *(const f16x8*)(hr + 32 + lq * 8);   // h1/h2 k32-63
    if (doL2) {  // L2(p): K=96 over [h1(p); h2(p-1)]
      const f16x8 f2 = *(const f16x8*)(hr + 64 + lq * 8);
      f32x4 dH[3];
#pragma unroll
      for (int i = 0; i < 3; ++i) {
        dH[i][0] = bias2r[i]; dH[i][1] = bias2r[i];
        dH[i][2] = bias2r[i]; dH[i][3] = bias2r[i];
      }
#pragma unroll
      for (int i = 0; i < 3; ++i)
        dH[i] = __builtin_amdgcn_mfma_f32_16x16x32_f16(f0, b2f[i][0], dH[i], 0, 0, 0);
#pragma unroll
      for (int i = 0; i < 3; ++i)
        dH[i] = __builtin_amdgcn_mfma_f32_16x16x32_f16(f1, b2f[i][1], dH[i], 0, 0, 0);
#pragma unroll
      for (int i = 0; i < 3; ++i)
        dH[i] = __builtin_amdgcn_mfma_f32_16x16x32_f16(f2, b2f[i][2], dH[i], 0, 0, 0);
      if (lq < 2) {
#pragma unroll
        for (int i = 0; i < 3; ++i)
#pragma unroll
          for (int r = 0; r < 4; ++r)
            gs2[lq * 4 + r][w * 48 + i * 16 + lj] = dH[i][r];
      }
    }
    if (doL1) {  // L1(p+1): C = xg(p+1) (xgA if p odd, xgB if p even), K=48
      f32x4 cH[3];
#pragma unroll
      for (int i = 0; i < 3; ++i) {
        const f32x4 xc = (p & 1) ? xgA[i] : xgB[i];
        cH[i] = __builtin_amdgcn_mfma_f32_16x16x32_f16(f0, b1[i][0], xc, 0, 0, 0);
      }
#pragma unroll
      for (int i = 0; i < 3; ++i)
        cH[i] = __builtin_amdgcn_mfma_f32_16x16x32_f16(f1, b1[i][1], cH[i], 0, 0, 0);
      if (lq < 2) {
#pragma unroll
        for (int i = 0; i < 3; ++i)
#pragma unroll
          for (int r = 0; r < 4; ++r)
            gs1[lq * 4 + r][w * 48 + i * 16 + lj] = cH[i][r];
      }
    }
    if (fcth && p >= 1) {  // fc logits of step p-1 (10 tasks per wave)
      float a = fcbr;
#pragma unroll
      for (int uq = 0; uq < 12; ++uq) {
        f32x4 hv = *(const f32x4*)&h2f[fn][uq * 4];
        f32x4 wv = *(const f32x4*)&fcws[fk * 48 + uq * 4];
        a += hv[0] * wv[0] + hv[1] * wv[1] + hv[2] * wv[2] + hv[3] * wv[3];
      }
      logit_s[fk][fn] = a;
    }
    if (stth && p >= 2) {  // store probs of step p-2
      out[(((size_t)b * P_ + (p - 2)) * 5 + sk) * T_ + t0 + sn] = prob_s[sk][sn];
    }
    if (doProd) {  // paired inGEMM with PRELOADED cg; then prefetch next cg
      f32x4 xgP[3];
      INGEMM(xgP, prodRB, cgCE, cgCO);
#pragma unroll
      for (int i = 0; i < 3; ++i) {
        xgA[i] = xgP[i];
#pragma unroll
        for (int r = 0; r < 4; ++r) xgB[i][r] = __shfl_xor((float)xgP[i][r], 32);
      }
      if (p <= 82) {  // cg for the pair produced at p+2 (2-iter distance)
#pragma unroll
        for (int i = 0; i < 3; ++i) { cgCE[i] = cgp[i * 16]; cgCO[i] = cgp[G_ + i * 16]; }
        cgp += 2 * G_;
      }
    }
    lds_barrier();
    // ================= V: activation phase (3 balanced tasks/thread) =======
    // slot0: L2 act (n=s0n, u=s0u) — gates prescaled, exp2 activations
    if (doL2) {
      const float ig = gs2[s0n][s0u], fg = gs2[s0n][48 + s0u];
      const float gg = gs2[s0n][96 + s0u], og = gs2[s0n][144 + s0u];
      const float cc = sig2(fg) * cS0 + sig2(ig) * tanh2g(gg);
      cS0 = cc;
      const float h = sig2(og) * tanh_c(cc);
      h12[s0n][48 + s0u] = (_Float16)h;
      h2f[s0n][s0u] = h;
    }
    // slot1: L2 for waves 0-1, L1 for waves 2-3 (wave-uniform branch)
    if (s1L2) {
      if (doL2) {
        const float ig = gs2[s1n][s1u], fg = gs2[s1n][48 + s1u];
        const float gg = gs2[s1n][96 + s1u], og = gs2[s1n][144 + s1u];
        const float cc = sig2(fg) * cS1 + sig2(ig) * tanh2g(gg);
        cS1 = cc;
        const float h = sig2(og) * tanh_c(cc);
        h12[s1n][48 + s1u] = (_Float16)h;
        h2f[s1n][s1u] = h;
      }
    } else {
      if (doL1) {
        const float ig = gs1[s1n][s1u], fg = gs1[s1n][48 + s1u];
        const float gg = gs1[s1n][96 + s1u], og = gs1[s1n][144 + s1u];
        const float cc = sig2(fg) * cS1 + sig2(ig) * tanh2g(gg);
        cS1 = cc;
        h12[s1n][s1u] = (_Float16)(sig2(og) * tanh_c(cc));
      }
    }
    // slot2: L1 act (n=s2n, u=s2u)
    if (doL1) {
      const float ig = gs1[s2n][s2u], fg = gs1[s2n][48 + s2u];
      const float gg = gs1[s2n][96 + s2u], og = gs1[s2n][144 + s2u];
      const float cc = sig2(fg) * cS2 + sig2(ig) * tanh2g(gg);
      cS2 = cc;
      h12[s2n][s2u] = (_Float16)(sig2(og) * tanh_c(cc));
    }
    if (smth && p >= 1) {  // softmax of step p-1 (logits from M(p))
      const int n = smn;
      const float l0 = logit_s[0][n], l1 = logit_s[1][n], l2 = logit_s[2][n],
                  l3 = logit_s[3][n], l4 = logit_s[4][n];
      const float m = fmaxf(fmaxf(fmaxf(l0, l1), fmaxf(l2, l3)), l4);
      const float e0 = __expf(l0 - m), e1 = __expf(l1 - m), e2 = __expf(l2 - m),
                  e3 = __expf(l3 - m), e4 = __expf(l4 - m);
      const float rs = __builtin_amdgcn_rcpf(e0 + e1 + e2 + e3 + e4);
      prob_s[0][n] = e0 * rs; prob_s[1][n] = e1 * rs; prob_s[2][n] = e2 * rs;
      prob_s[3][n] = e3 * rs; prob_s[4][n] = e4 * rs;
    }
    // rotate pf carry: pvN (slice p+5) becomes next iter's pvC (slice (p+1)+4)
#pragma unroll
    for (int it = 0; it < 6; ++it) pvC[it] = pvN[it];
    lds_barrier();
  }
  // ---- epilogue: fc(87) + store(86); softmax(87); store(87) ----
  if (fcth) {
    float a = fcbr;
#pragma unroll
    for (int uq = 0; uq < 12; ++uq) {
      f32x4 hv = *(const f32x4*)&h2f[fn][uq * 4];
      f32x4 wv = *(const f32x4*)&fcws[fk * 48 + uq * 4];
      a += hv[0] * wv[0] + hv[1] * wv[1] + hv[2] * wv[2] + hv[3] * wv[3];
    }
    logit_s[fk][fn] = a;
  }
  if (stth) {
    out[(((size_t)b * P_ + (P_ - 2)) * 5 + sk) * T_ + t0 + sn] = prob_s[sk][sn];
  }
  lds_barrier();
  if (smth) {
    const int n = smn;
    const float l0 = logit_s[0][n], l1 = logit_s[1][n], l2 = logit_s[2][n],
                l3 = logit_s[3][n], l4 = logit_s[4][n];
    const float m = fmaxf(fmaxf(fmaxf(l0, l1), fmaxf(l2, l3)), l4);
    const float e0 = __expf(l0 - m), e1 = __expf(l1 - m), e2 = __expf(l2 - m),
                e3 = __expf(l3 - m), e4 = __expf(l4 - m);
    const float rs = __builtin_amdgcn_rcpf(e0 + e1 + e2 + e3 + e4);
    prob_s[0][n] = e0 * rs; prob_s[1][n] = e1 * rs; prob_s[2][n] = e2 * rs;
    prob_s[3][n] = e3 * rs; prob_s[4][n] = e4 * rs;
  }
  lds_barrier();
  if (stth) {
    out[(((size_t)b * P_ + (P_ - 1)) * 5 + sk) * T_ + t0 + sn] = prob_s[sk][sn];
  }
}

extern "C" void kernel_launch(void* const* d_in, const int* in_sizes, int n_in,
                              void* d_out, int out_size, void* d_ws, size_t ws_size,
                              hipStream_t stream) {
  const float* pf   = (const float*)d_in[0];
  const float* pc   = (const float*)d_in[1];
  const float* fc1w = (const float*)d_in[2];
  const float* fc1b = (const float*)d_in[3];
  const float* fc2w = (const float*)d_in[4];
  const float* fc2b = (const float*)d_in[5];
  const float* fc3w = (const float*)d_in[6];
  const float* fc3b = (const float*)d_in[7];
  const float* wih1 = (const float*)d_in[8];
  const float* whh1 = (const float*)d_in[9];
  const float* bih1 = (const float*)d_in[10];
  const float* bhh1 = (const float*)d_in[11];
  const float* wih2 = (const float*)d_in[12];
  const float* whh2 = (const float*)d_in[13];
  const float* bih2 = (const float*)d_in[14];
  const float* bhh2 = (const float*)d_in[15];
  const float* fcw  = (const float*)d_in[16];
  const float* fcb  = (const float*)d_in[17];
  float* out = (float*)d_out;

  float* ctxg = (float*)d_ws;  // (B*P) x 192 fp32 = ~1.08 MB

  ctx_kernel<<<22, 64, 0, stream>>>(pc, fc1w, fc1b, fc2w, fc2b, fc3w, fc3b,
                                    wih1, bih1, bhh1, ctxg);
  scan_fused<<<N_ / 8, 256, 0, stream>>>(pf, ctxg, wih1, whh1, wih2, whh2,
                                         bih2, bhh2, fcw, fcb, out);
}

// Round 23
// 353.793 us; speedup vs baseline: 1.0174x; 1.0174x over previous
//
#include <hip/hip_runtime.h>
#include <hip/hip_bf16.h>
#include <cstdint>

#define P_ 88   // pitches (sequence length of the scan)
#define B_ 16   // batch
#define T_ 256  // timesteps (folded into batch N)
#define H_ 188  // per-pitch features
#define G_ 192  // 4*48 gates; also LSTM1 input size (188 feat + 4 ctx)
#define U_ 48   // LSTM units
#define N_ 4096 // B_*T_

typedef __attribute__((ext_vector_type(8))) _Float16 f16x8;
typedef __attribute__((ext_vector_type(4))) float f32x4;

__device__ __forceinline__ float sigf(float x) {
  return __builtin_amdgcn_rcpf(1.0f + __expf(-x));
}
__device__ __forceinline__ float tanh_f(float x) {
  return 1.0f - 2.0f * __builtin_amdgcn_rcpf(1.0f + __expf(2.0f * x));
}

// Relaxed workgroup barrier: waits only on LDS ops (lgkmcnt), NOT vmcnt —
// global loads issued before it stay in flight across it.
__device__ __forceinline__ void lds_barrier() {
  asm volatile("s_waitcnt lgkmcnt(0)\n\ts_barrier" ::: "memory");
}

// ---------------------------------------------------------------------------
// Kernel 1: context MLP -> per-(b,p) gate bias vector (incl. bih1+bhh1).
// ---------------------------------------------------------------------------
__global__ void ctx_kernel(const float* __restrict__ pc,
                           const float* __restrict__ fc1w, const float* __restrict__ fc1b,
                           const float* __restrict__ fc2w, const float* __restrict__ fc2b,
                           const float* __restrict__ fc3w, const float* __restrict__ fc3b,
                           const float* __restrict__ wih1,
                           const float* __restrict__ bih1, const float* __restrict__ bhh1,
                           float* __restrict__ ctxg) {
  int bp = blockIdx.x * 64 + threadIdx.x;
  if (bp >= B_ * P_) return;
  float p0 = pc[bp * 3 + 0], p1 = pc[bp * 3 + 1], p2 = pc[bp * 3 + 2];
  float x1[16], x2[16];
#pragma unroll
  for (int jj = 0; jj < 16; ++jj)
    x1[jj] = fmaxf(0.f, fc1w[jj * 3 + 0] * p0 + fc1w[jj * 3 + 1] * p1 + fc1w[jj * 3 + 2] * p2 + fc1b[jj]);
#pragma unroll
  for (int jj = 0; jj < 16; ++jj) {
    float s = fc2b[jj];
#pragma unroll
    for (int i = 0; i < 16; ++i) s += fc2w[jj * 16 + i] * x1[i];
    x2[jj] = fmaxf(0.f, s);
  }
  float ce[4];
#pragma unroll
  for (int jj = 0; jj < 4; ++jj) {
    float s = fc3b[jj];
#pragma unroll
    for (int i = 0; i < 16; ++i) s += fc3w[jj * 16 + i] * x2[i];
    ce[jj] = s;
  }
  float* op = ctxg + (size_t)bp * G_;
  for (int g = 0; g < G_; ++g) {
    const float* wr = wih1 + (size_t)g * G_ + H_;
    op[g] = bih1[g] + bhh1[g] + ce[0] * wr[0] + ce[1] * wr[1] + ce[2] * wr[2] + ce[3] * wr[3];
  }
}

// ---------------------------------------------------------------------------
// Kernel 2: FUSED scan + PAIRED input GEMM + XCD swizzle
// + BALANCED 3-task activation (round-21 best configuration, 354 µs).
// ---------------------------------------------------------------------------
__global__ __launch_bounds__(256, 2) void scan_fused(
    const float* __restrict__ pf, const float* __restrict__ ctxg,
    const float* __restrict__ wih1, const float* __restrict__ whh1,
    const float* __restrict__ wih2, const float* __restrict__ whh2,
    const float* __restrict__ bih2, const float* __restrict__ bhh2,
    const float* __restrict__ fcw, const float* __restrict__ fcb,
    float* __restrict__ out) {
  __shared__ __align__(16) _Float16 h12[16][104];  // cols 0-47 h1, 48-95 h2
  __shared__ __align__(16) float gs1[8][196];      // L1 gate staging
  __shared__ __align__(16) float gs2[8][196];      // L2 gate staging
  __shared__ __align__(16) float h2f[8][52];       // h2 fp32 for fc_states
  __shared__ __align__(16) float fcws[5 * 48];
  __shared__ float logit_s[5][8];
  __shared__ float prob_s[5][8];
  // pf pair buffers: rows 0-7 = even slice, rows 8-15 = odd slice of pair m;
  // buffer index = m & 1.
  __shared__ __align__(16) _Float16 pfhi[2][16][200];
  __shared__ __align__(16) _Float16 pflo[2][16][200];

  const int tid = threadIdx.x;
  const int w = tid >> 6, l = tid & 63;
  const int lj = l & 15, lq = l >> 4;
  // XCD-aware bijective swizzle (512 blocks, chunk 64): XCD x owns batches
  // 2x, 2x+1 -> same-b scattered pf reads dedupe in that XCD's L2.
  const int g512 = (blockIdx.x & 7) * 64 + (blockIdx.x >> 3);
  const int n0 = g512 * 8;
  const int b = n0 >> 8, t0 = n0 & 255;

  // ---- persistent weight B-fragments (f16): recurrent + input GEMM ----
  f16x8 b1[3][2];    // whh1 cols, K=48 pad 64
  f16x8 b2f[3][3];   // [wih2; whh2] cols, K=96
  f16x8 wf[3][6];    // wih1 feature cols, K=188 pad 192
  float bias2r[3];
#pragma unroll
  for (int i = 0; i < 3; ++i) {
    const int j = w * 48 + i * 16 + lj;
    bias2r[i] = bih2[j] + bhh2[j];
#pragma unroll
    for (int kc = 0; kc < 2; ++kc)
#pragma unroll
      for (int e = 0; e < 8; ++e) {
        const int u = kc * 32 + lq * 8 + e;
        b1[i][kc][e] = (u < U_) ? (_Float16)whh1[j * U_ + u] : (_Float16)0.f;
      }
#pragma unroll
    for (int kc = 0; kc < 3; ++kc)
#pragma unroll
      for (int e = 0; e < 8; ++e) {
        const int k = kc * 32 + lq * 8 + e;
        b2f[i][kc][e] = (k < U_) ? (_Float16)wih2[j * U_ + k]
                                 : (_Float16)whh2[j * U_ + (k - U_)];
      }
#pragma unroll
    for (int kc = 0; kc < 6; ++kc)
#pragma unroll
      for (int e = 0; e < 8; ++e) {
        const int k = kc * 32 + lq * 8 + e;
        wf[i][kc][e] = (k < H_) ? (_Float16)wih1[(size_t)j * G_ + k] : (_Float16)0.f;
      }
  }

  // ---- zero LDS state, load fc weights ----
  for (int e = tid; e < 16 * 104 / 2; e += 256) ((unsigned*)h12)[e] = 0u;
  for (int e = tid; e < 3200; e += 256) {  // 2*16*200 halves = 3200 uints each
    ((unsigned*)pfhi)[e] = 0u;
    ((unsigned*)pflo)[e] = 0u;
  }
  for (int e = tid; e < 5 * U_; e += 256) fcws[e] = fcw[e];
  lds_barrier();  // zeros complete before staging writes

  // ---- BALANCED activation tasks: flat f = tid, tid+256, tid+512 over
  // 768 = [0,384) L2 + [384,768) L1. Slot types are wave-uniform:
  //   slot0: L2 task tid                 (all threads)
  //   slot1: tid<128 -> L2 task tid+256; tid>=128 -> L1 task tid-128
  //   slot2: L1 task tid+128             (all threads)
  const int s0n = tid / U_, s0u = tid % U_;                 // L2
  const bool s1L2 = (tid < 128);
  const int s1f = s1L2 ? (tid + 256) : (tid - 128);
  const int s1n = s1f / U_, s1u = s1f % U_;                 // L2 or L1
  const int s2n = (tid + 128) / U_, s2u = (tid + 128) % U_; // L1
  float cS0 = 0.f, cS1 = 0.f, cS2 = 0.f;  // c-state per slot (type fixed per thread)

  // aux roles: fc lanes 40-49 of EVERY wave; store tid 96-135; softmax 192-199.
  const bool fcth = (l >= 40 && l < 50);
  const int fi = w * 10 + (l - 40);
  const int fk = (fi >> 3) < 5 ? (fi >> 3) : 0, fn = fi & 7;
  const float fcbr = fcth ? fcb[fk] : 0.f;
  const bool stth = tid >= 96 && tid < 136;
  const int sk = (tid - 96) >> 3, sn = (tid - 96) & 7;
  const bool smth = tid >= 192 && tid < 200;
  const int smn = tid - 192;

  // ---- pf staging coords: thread covers (h = tid/8 + 32*it, t = t0 + tid%8) ----
  const int sh = tid >> 3, stl = tid & 7;
  const float* pfb = pf + (size_t)b * P_ * H_ * T_ + (size_t)sh * T_ + t0 + stl;

  // prologue: stage slices 0,1 -> buf0 rows {0-7},{8-15}; slices 2,3 -> buf1
#pragma unroll
  for (int s = 0; s < 4; ++s) {
    const int bufi = (s >> 1) & 1, row = (s & 1) * 8 + stl;
    const float* sp = pfb + (size_t)s * H_ * T_;
#pragma unroll
    for (int it = 0; it < 6; ++it) {
      const int h = sh + it * 32;
      if (h < H_) {
        const float v = sp[(size_t)it * 32 * T_];
        const _Float16 hi = (_Float16)v;
        pfhi[bufi][row][h] = hi;
        pflo[bufi][row][h] = (_Float16)(v - (float)hi);
      }
    }
  }
  lds_barrier();

  // ctx-bias pointer (gate column w*48+i*16+lj)
  const float* cgbase = ctxg + (size_t)b * P_ * G_ + w * 48 + lj;

// INGEMM over pair buffer RB: C init = per-lane-half biases (CE/CO arrays)
#define INGEMM(ACC, RB, CE, CO)                                                \
  {                                                                            \
    _Pragma("unroll") for (int i = 0; i < 3; ++i) {                            \
      const float bsel = (l < 32) ? (CE)[i] : (CO)[i];                         \
      ACC[i][0] = bsel; ACC[i][1] = bsel; ACC[i][2] = bsel; ACC[i][3] = bsel;  \
    }                                                                          \
    _Pragma("unroll") for (int c = 0; c < 6; ++c) {                            \
      const f16x8 ah = *(const f16x8*)&pfhi[RB][lj][c * 32 + lq * 8];          \
      const f16x8 al = *(const f16x8*)&pflo[RB][lj][c * 32 + lq * 8];          \
      ACC[0] = __builtin_amdgcn_mfma_f32_16x16x32_f16(ah, wf[0][c], ACC[0], 0, 0, 0); \
      ACC[1] = __builtin_amdgcn_mfma_f32_16x16x32_f16(ah, wf[1][c], ACC[1], 0, 0, 0); \
      ACC[2] = __builtin_amdgcn_mfma_f32_16x16x32_f16(ah, wf[2][c], ACC[2], 0, 0, 0); \
      ACC[0] = __builtin_amdgcn_mfma_f32_16x16x32_f16(al, wf[0][c], ACC[0], 0, 0, 0); \
      ACC[1] = __builtin_amdgcn_mfma_f32_16x16x32_f16(al, wf[1][c], ACC[1], 0, 0, 0); \
      ACC[2] = __builtin_amdgcn_mfma_f32_16x16x32_f16(al, wf[2][c], ACC[2], 0, 0, 0); \
    }                                                                          \
  }

  // prologue production: pair 0 -> xgA = xg(0) (lanes l<32), xgB = xg(1)
  f32x4 xgA[3], xgB[3];
  {
    float cgE[3], cgO[3];
#pragma unroll
    for (int i = 0; i < 3; ++i) { cgE[i] = cgbase[i * 16]; cgO[i] = cgbase[G_ + i * 16]; }
    f32x4 xgP[3];
    INGEMM(xgP, 0, cgE, cgO);
#pragma unroll
    for (int i = 0; i < 3; ++i) {
      xgA[i] = xgP[i];
#pragma unroll
      for (int r = 0; r < 4; ++r) xgB[i][r] = __shfl_xor((float)xgP[i][r], 32);
    }
  }
  lds_barrier();  // buf0 reads complete before iter-0 staging rewrites it

  // cg for pair 1 (slices 2,3), preloaded; cgp points at pair 2 onward
  float cgCE[3], cgCO[3];
#pragma unroll
  for (int i = 0; i < 3; ++i) {
    cgCE[i] = cgbase[2 * G_ + i * 16];
    cgCO[i] = cgbase[3 * G_ + i * 16];
  }
  const float* cgp = cgbase + 4 * G_;

  // pf value carry registers: pvC = slice p+4 (written this iter),
  // pvN = slice p+5 (issued this iter, written next iter).
  float pvC[6], pvN[6];
#pragma unroll
  for (int it = 0; it < 6; ++it) { pvC[it] = 0.f; pvN[it] = 0.f; }
  const float* pfstage = pfb + (size_t)4 * H_ * T_;   // slice 4 onward

  for (int p = -1; p < P_; ++p) {
    const bool doL2 = (p >= 0), doL1 = (p < P_ - 1);
    const bool doProd = ((p & 1) == 0) && (p <= 84);   // pair (p+2, p+3)
    const bool doWrite = (p >= 0 && p <= 83);          // LDS-write slice p+4
    const bool doIssue = (p <= 82);                    // issue loads slice p+5
    const int prodRB = ((p + 2) >> 1) & 1;
    const int stgRB = ((p + 4) >> 1) & 1, stgRow = ((p + 4) & 1) * 8 + stl;

    // ---- write pvC (slice p+4, loaded LAST iter -> latency already hidden) ----
    if (doWrite) {
#pragma unroll
      for (int it = 0; it < 6; ++it) {
        const int h = sh + it * 32;
        if (h < H_) {
          const _Float16 hi = (_Float16)pvC[it];
          pfhi[stgRB][stgRow][h] = hi;
          pflo[stgRB][stgRow][h] = (_Float16)(pvC[it] - (float)hi);
        }
      }
    }
    // ---- issue slice p+5 loads; consumed next iteration (cross-barrier) ----
    if (doIssue) {
#pragma unroll
      for (int it = 0; it < 6; ++it)
        pvN[it] = (sh + it * 32 < H_) ? pfstage[(size_t)it * 32 * T_] : 0.f;
      pfstage += (size_t)H_ * T_;
    }

    // ================= M: MFMA phase =================
    __builtin_amdgcn_s_setprio(1);
    const _Float16* hr = &h12[lj][0];
    const f16x8 f0 = *(const f16x8*)(hr + lq * 8);        // h1 k0-31
    const f16x8 f1 = *(const f16x8*)(hr + 32 + lq * 8);   // h1/h2 k32-63
    if (doL2) {  // L2(p): K=96 over [h1(p); h2(p-1)]
      const f16x8 f2 = *(const f16x8*)(hr + 64 + lq * 8);
      f32x4 dH[3];
#pragma unroll
      for (int i = 0; i < 3; ++i) {
        dH[i][0] = bias2r[i]; dH[i][1] = bias2r[i];
        dH[i][2] = bias2r[i]; dH[i][3] = bias2r[i];
      }
#pragma unroll
      for (int i = 0; i < 3; ++i)
        dH[i] = __builtin_amdgcn_mfma_f32_16x16x32_f16(f0, b2f[i][0], dH[i], 0, 0, 0);
#pragma unroll
      for (int i = 0; i < 3; ++i)
        dH[i] = __builtin_amdgcn_mfma_f32_16x16x32_f16(f1, b2f[i][1], dH[i], 0, 0, 0);
#pragma unroll
      for (int i = 0; i < 3; ++i)
        dH[i] = __builtin_amdgcn_mfma_f32_16x16x32_f16(f2, b2f[i][2], dH[i], 0, 0, 0);
      if (lq < 2) {
#pragma unroll
        for (int i = 0; i < 3; ++i)
#pragma unroll
          for (int r = 0; r < 4; ++r)
            gs2[lq * 4 + r][w * 48 + i * 16 + lj] = dH[i][r];
      }
    }
    if (doL1) {  // L1(p+1): C = xg(p+1) (xgA if p odd, xgB if p even), K=48
      f32x4 cH[3];
#pragma unroll
      for (int i = 0; i < 3; ++i) {
        const f32x4 xc = (p & 1) ? xgA[i] : xgB[i];
        cH[i] = __builtin_amdgcn_mfma_f32_16x16x32_f16(f0, b1[i][0], xc, 0, 0, 0);
      }
#pragma unroll
      for (int i = 0; i < 3; ++i)
        cH[i] = __builtin_amdgcn_mfma_f32_16x16x32_f16(f1, b1[i][1], cH[i], 0, 0, 0);
      if (lq < 2) {
#pragma unroll
        for (int i = 0; i < 3; ++i)
#pragma unroll
          for (int r = 0; r < 4; ++r)
            gs1[lq * 4 + r][w * 48 + i * 16 + lj] = cH[i][r];
      }
    }
    __builtin_amdgcn_s_setprio(0);
    if (fcth && p >= 1) {  // fc logits of step p-1 (10 tasks per wave)
      float a = fcbr;
#pragma unroll
      for (int uq = 0; uq < 12; ++uq) {
        f32x4 hv = *(const f32x4*)&h2f[fn][uq * 4];
        f32x4 wv = *(const f32x4*)&fcws[fk * 48 + uq * 4];
        a += hv[0] * wv[0] + hv[1] * wv[1] + hv[2] * wv[2] + hv[3] * wv[3];
      }
      logit_s[fk][fn] = a;
    }
    if (stth && p >= 2) {  // store probs of step p-2
      out[(((size_t)b * P_ + (p - 2)) * 5 + sk) * T_ + t0 + sn] = prob_s[sk][sn];
    }
    if (doProd) {  // paired inGEMM with PRELOADED cg; then prefetch next cg
      f32x4 xgP[3];
      INGEMM(xgP, prodRB, cgCE, cgCO);
#pragma unroll
      for (int i = 0; i < 3; ++i) {
        xgA[i] = xgP[i];
#pragma unroll
        for (int r = 0; r < 4; ++r) xgB[i][r] = __shfl_xor((float)xgP[i][r], 32);
      }
      if (p <= 82) {  // cg for the pair produced at p+2 (2-iter distance)
#pragma unroll
        for (int i = 0; i < 3; ++i) { cgCE[i] = cgp[i * 16]; cgCO[i] = cgp[G_ + i * 16]; }
        cgp += 2 * G_;
      }
    }
    lds_barrier();
    // ================= V: activation phase (3 balanced tasks/thread) =======
    // slot0: L2 act (n=s0n, u=s0u)
    if (doL2) {
      const float ig = gs2[s0n][s0u], fg = gs2[s0n][48 + s0u];
      const float gg = gs2[s0n][96 + s0u], og = gs2[s0n][144 + s0u];
      const float cc = sigf(fg) * cS0 + sigf(ig) * tanh_f(gg);
      cS0 = cc;
      const float h = sigf(og) * tanh_f(cc);
      h12[s0n][48 + s0u] = (_Float16)h;
      h2f[s0n][s0u] = h;
    }
    // slot1: L2 for waves 0-1, L1 for waves 2-3 (wave-uniform branch)
    if (s1L2) {
      if (doL2) {
        const float ig = gs2[s1n][s1u], fg = gs2[s1n][48 + s1u];
        const float gg = gs2[s1n][96 + s1u], og = gs2[s1n][144 + s1u];
        const float cc = sigf(fg) * cS1 + sigf(ig) * tanh_f(gg);
        cS1 = cc;
        const float h = sigf(og) * tanh_f(cc);
        h12[s1n][48 + s1u] = (_Float16)h;
        h2f[s1n][s1u] = h;
      }
    } else {
      if (doL1) {
        const float ig = gs1[s1n][s1u], fg = gs1[s1n][48 + s1u];
        const float gg = gs1[s1n][96 + s1u], og = gs1[s1n][144 + s1u];
        const float cc = sigf(fg) * cS1 + sigf(ig) * tanh_f(gg);
        cS1 = cc;
        h12[s1n][s1u] = (_Float16)(sigf(og) * tanh_f(cc));
      }
    }
    // slot2: L1 act (n=s2n, u=s2u)
    if (doL1) {
      const float ig = gs1[s2n][s2u], fg = gs1[s2n][48 + s2u];
      const float gg = gs1[s2n][96 + s2u], og = gs1[s2n][144 + s2u];
      const float cc = sigf(fg) * cS2 + sigf(ig) * tanh_f(gg);
      cS2 = cc;
      h12[s2n][s2u] = (_Float16)(sigf(og) * tanh_f(cc));
    }
    if (smth && p >= 1) {  // softmax of step p-1 (logits from M(p))
      const int n = smn;
      const float l0 = logit_s[0][n], l1 = logit_s[1][n], l2 = logit_s[2][n],
                  l3 = logit_s[3][n], l4 = logit_s[4][n];
      const float m = fmaxf(fmaxf(fmaxf(l0, l1), fmaxf(l2, l3)), l4);
      const float e0 = __expf(l0 - m), e1 = __expf(l1 - m), e2 = __expf(l2 - m),
                  e3 = __expf(l3 - m), e4 = __expf(l4 - m);
      const float rs = __builtin_amdgcn_rcpf(e0 + e1 + e2 + e3 + e4);
      prob_s[0][n] = e0 * rs; prob_s[1][n] = e1 * rs; prob_s[2][n] = e2 * rs;
      prob_s[3][n] = e3 * rs; prob_s[4][n] = e4 * rs;
    }
    // rotate pf carry: pvN (slice p+5) becomes next iter's pvC (slice (p+1)+4)
#pragma unroll
    for (int it = 0; it < 6; ++it) pvC[it] = pvN[it];
    lds_barrier();
  }
  // ---- epilogue: fc(87) + store(86); softmax(87); store(87) ----
  if (fcth) {
    float a = fcbr;
#pragma unroll
    for (int uq = 0; uq < 12; ++uq) {
      f32x4 hv = *(const f32x4*)&h2f[fn][uq * 4];
      f32x4 wv = *(const f32x4*)&fcws[fk * 48 + uq * 4];
      a += hv[0] * wv[0] + hv[1] * wv[1] + hv[2] * wv[2] + hv[3] * wv[3];
    }
    logit_s[fk][fn] = a;
  }
  if (stth) {
    out[(((size_t)b * P_ + (P_ - 2)) * 5 + sk) * T_ + t0 + sn] = prob_s[sk][sn];
  }
  lds_barrier();
  if (smth) {
    const int n = smn;
    const float l0 = logit_s[0][n], l1 = logit_s[1][n], l2 = logit_s[2][n],
                l3 = logit_s[3][n], l4 = logit_s[4][n];
    const float m = fmaxf(fmaxf(fmaxf(l0, l1), fmaxf(l2, l3)), l4);
    const float e0 = __expf(l0 - m), e1 = __expf(l1 - m), e2 = __expf(l2 - m),
                e3 = __expf(l3 - m), e4 = __expf(l4 - m);
    const float rs = __builtin_amdgcn_rcpf(e0 + e1 + e2 + e3 + e4);
    prob_s[0][n] = e0 * rs; prob_s[1][n] = e1 * rs; prob_s[2][n] = e2 * rs;
    prob_s[3][n] = e3 * rs; prob_s[4][n] = e4 * rs;
  }
  lds_barrier();
  if (stth) {
    out[(((size_t)b * P_ + (P_ - 1)) * 5 + sk) * T_ + t0 + sn] = prob_s[sk][sn];
  }
}

extern "C" void kernel_launch(void* const* d_in, const int* in_sizes, int n_in,
                              void* d_out, int out_size, void* d_ws, size_t ws_size,
                              hipStream_t stream) {
  const float* pf   = (const float*)d_in[0];
  const float* pc   = (const float*)d_in[1];
  const float* fc1w = (const float*)d_in[2];
  const float* fc1b = (const float*)d_in[3];
  const float* fc2w = (const float*)d_in[4];
  const float* fc2b = (const float*)d_in[5];
  const float* fc3w = (const float*)d_in[6];
  const float* fc3b = (const float*)d_in[7];
  const float* wih1 = (const float*)d_in[8];
  const float* whh1 = (const float*)d_in[9];
  const float* bih1 = (const float*)d_in[10];
  const float* bhh1 = (const float*)d_in[11];
  const float* wih2 = (const float*)d_in[12];
  const float* whh2 = (const float*)d_in[13];
  const float* bih2 = (const float*)d_in[14];
  const float* bhh2 = (const float*)d_in[15];
  const float* fcw  = (const float*)d_in[16];
  const float* fcb  = (const float*)d_in[17];
  float* out = (float*)d_out;

  float* ctxg = (float*)d_ws;  // (B*P) x 192 fp32 = ~1.08 MB

  ctx_kernel<<<22, 64, 0, stream>>>(pc, fc1w, fc1b, fc2w, fc2b, fc3w, fc3b,
                                    wih1, bih1, bhh1, ctxg);
  scan_fused<<<N_ / 8, 256, 0, stream>>>(pf, ctxg, wih1, whh1, wih2, whh2,
                                         bih2, bhh2, fcw, fcb, out);
}